// Round 1
// baseline (1093.649 us; speedup 1.0000x reference)
//
#include <hip/hip_runtime.h>

#define B_      64
#define LC_     4096
#define H_      768
#define P_      128
#define MAXLEN_ 4096
#define BUDGET_ 200.0f

// Workspace layout (bytes):
//   s_ws  @ 0        : B*LC floats   (1 MiB)  raw scores (dot + t[b], no mask)
//   v_ws  @ 1<<20    : B*H floats    (192 KiB) v[b,h] = q[b,:] @ Wc[h,:]^T
//   t_ws  @ 1<<20 + B_*H_*4 : B floats         t[b] = q[b,:] . bc
// total ~1.25 MiB

// ---------------- K1: tiny projections -> v, t ----------------
__global__ __launch_bounds__(256) void k1_proj(
    const float* __restrict__ qr,   // [B,1,H]
    const float* __restrict__ Wq,   // [H,P]
    const float* __restrict__ bq,   // [P]
    const float* __restrict__ Wc,   // [H,P]
    const float* __restrict__ bc,   // [P]
    float* __restrict__ v_ws,       // [B,H]
    float* __restrict__ t_ws)       // [B]
{
    const int b = blockIdx.x;
    const int t = threadIdx.x;
    __shared__ float qr_s[H_];
    __shared__ float part[256];
    __shared__ float q_s[P_];

    for (int h = t; h < H_; h += 256) qr_s[h] = qr[b * H_ + h];
    __syncthreads();

    // q[b,p] = sum_h qr[b,h]*Wq[h,p] + bq[p]; split h-range across 2 halves
    const int p    = t & (P_ - 1);
    const int half = t >> 7;
    const int h0   = half * (H_ / 2);
    float acc = 0.f;
    #pragma unroll 8
    for (int h = 0; h < H_ / 2; ++h)
        acc += qr_s[h0 + h] * Wq[(h0 + h) * P_ + p];   // coalesced across p
    part[t] = acc;
    __syncthreads();
    if (t < P_) q_s[t] = part[t] + part[t + P_] + bq[t];
    __syncthreads();

    // v[b,h] = sum_p q[p] * Wc[h,p]
    const float4* wc4 = reinterpret_cast<const float4*>(Wc);
    for (int h = t; h < H_; h += 256) {
        float a = 0.f;
        #pragma unroll 8
        for (int pp = 0; pp < P_ / 4; ++pp) {
            float4 w = wc4[h * (P_ / 4) + pp];
            a += q_s[pp * 4 + 0] * w.x + q_s[pp * 4 + 1] * w.y
               + q_s[pp * 4 + 2] * w.z + q_s[pp * 4 + 3] * w.w;
        }
        v_ws[b * H_ + h] = a;
    }
    if (t == 0) {
        float tb = 0.f;
        for (int pp = 0; pp < P_; ++pp) tb += q_s[pp] * bc[pp];
        t_ws[b] = tb;
    }
}

// ---------------- K2: streaming matvec scores ----------------
// grid (B, LC/64), block 256 = 4 waves; each wave: 16 rows, one row = 768-dot
__global__ __launch_bounds__(256) void k2_scores(
    const float* __restrict__ ctx,  // [B,LC,H]
    const float* __restrict__ v_ws, // [B,H]
    const float* __restrict__ t_ws, // [B]
    float* __restrict__ s_ws)       // [B,LC]
{
    const int b    = blockIdx.x;
    const int wave = threadIdx.x >> 6;
    const int lane = threadIdx.x & 63;

    const float4* v4 = reinterpret_cast<const float4*>(v_ws + b * H_);
    const float4 v0 = v4[lane];
    const float4 v1 = v4[64 + lane];
    const float4 v2 = v4[128 + lane];
    const float  tb = t_ws[b];

    const int j0 = blockIdx.y * 64 + wave * 16;
    const float4* base =
        reinterpret_cast<const float4*>(ctx + ((size_t)b * LC_ + j0) * H_);

    #pragma unroll 4
    for (int jj = 0; jj < 16; ++jj) {
        const float4* row = base + (size_t)jj * (H_ / 4);
        float4 a = row[lane];
        float4 c = row[64 + lane];
        float4 d = row[128 + lane];
        float acc = a.x * v0.x + a.y * v0.y + a.z * v0.z + a.w * v0.w
                  + c.x * v1.x + c.y * v1.y + c.z * v1.z + c.w * v1.w
                  + d.x * v2.x + d.y * v2.y + d.z * v2.z + d.w * v2.w;
        #pragma unroll
        for (int off = 32; off; off >>= 1) acc += __shfl_xor(acc, off, 64);
        if (lane == 0) s_ws[b * LC_ + j0 + jj] = acc + tb;
    }
}

// ---------------- K3: budget projection (bisection) + token scatter ----------------
__global__ __launch_bounds__(256) void k3_project(
    const float* __restrict__ s_ws,   // [B,LC] raw scores
    const int*   __restrict__ mask,   // [B,LC]
    const int*   __restrict__ qe_arr, // [B]
    float* __restrict__ out)          // [B,MAXLEN]
{
    const int b = blockIdx.x;
    const int t = threadIdx.x;
    const int wid  = t >> 6;
    const int lane = t & 63;

    __shared__ float s_lds[LC_];
    __shared__ float rmin[4], rmax[4], rsum[4];
    __shared__ int   rcnt[4];
    __shared__ float rbuf[2][4];

    float sreg[16];
    float lmin = 1e30f, lmax = -1e30f, lsum = 0.f;
    int   lcnt = 0;

    #pragma unroll
    for (int k = 0; k < 16; ++k) {
        const int i = t + k * 256;
        const int m = mask[b * LC_ + i];
        float val = s_ws[b * LC_ + i] + (float)(m - 1) * 100000.0f;  // mask penalty, TEMP=1
        sreg[k] = val;
        s_lds[i] = val;
        lmin = fminf(lmin, val);
        lmax = fmaxf(lmax, val);
        lsum += fminf(fmaxf(val, 0.f), 1.f);
        lcnt += m;
    }

    // block reduce min/max/feasible-sum/mask-count
    #pragma unroll
    for (int off = 32; off; off >>= 1) {
        lmin = fminf(lmin, __shfl_xor(lmin, off, 64));
        lmax = fmaxf(lmax, __shfl_xor(lmax, off, 64));
        lsum += __shfl_xor(lsum, off, 64);
        lcnt += __shfl_xor(lcnt, off, 64);
    }
    if (lane == 0) { rmin[wid] = lmin; rmax[wid] = lmax; rsum[wid] = lsum; rcnt[wid] = lcnt; }
    __syncthreads();
    const float gmin = fminf(fminf(rmin[0], rmin[1]), fminf(rmin[2], rmin[3]));
    const float gmax = fmaxf(fmaxf(rmax[0], rmax[1]), fmaxf(rmax[2], rmax[3]));
    const float gsum = rsum[0] + rsum[1] + rsum[2] + rsum[3];
    const int   gcnt = rcnt[0] + rcnt[1] + rcnt[2] + rcnt[3];

    const bool feasible = (gsum <= BUDGET_);
    float lo = gmin - 1.f;
    float hi = gmax;

    // 100 bisection iterations, one barrier each (double-buffered partials)
    for (int it = 0; it < 100; ++it) {
        const float mid = 0.5f * (lo + hi);
        float ps = 0.f;
        #pragma unroll
        for (int k = 0; k < 16; ++k)
            ps += fminf(fmaxf(sreg[k] - mid, 0.f), 1.f);
        #pragma unroll
        for (int off = 32; off; off >>= 1) ps += __shfl_xor(ps, off, 64);
        if (lane == 0) rbuf[it & 1][wid] = ps;
        __syncthreads();
        const float total = rbuf[it & 1][0] + rbuf[it & 1][1]
                          + rbuf[it & 1][2] + rbuf[it & 1][3];
        if (total > BUDGET_) lo = mid; else hi = mid;
    }

    const float tau  = feasible ? 0.f : 0.5f * (lo + hi);
    const int   qe   = qe_arr[b];
    const int   clen = gcnt - 1;   // context_length

    #pragma unroll
    for (int k = 0; k < 16; ++k) {
        const int pos = t + k * 256;
        const int idx = pos - qe + 1;
        float o;
        if (pos < qe)                        o = 1.f;
        else if (idx >= 1 && idx <= clen)    o = fminf(fmaxf(s_lds[idx] - tau, 0.f), 1.f);
        else                                 o = 0.f;
        out[b * MAXLEN_ + pos] = o;
    }
}

extern "C" void kernel_launch(void* const* d_in, const int* in_sizes, int n_in,
                              void* d_out, int out_size, void* d_ws, size_t ws_size,
                              hipStream_t stream) {
    const float* qr   = (const float*)d_in[0];  // question_reps [B,1,H]
    const float* ctx  = (const float*)d_in[1];  // context_reps  [B,LC,H]
    const float* Wq   = (const float*)d_in[2];  // [H,P]
    const float* bq   = (const float*)d_in[3];  // [P]
    const float* Wc   = (const float*)d_in[4];  // [H,P]
    const float* bc   = (const float*)d_in[5];  // [P]
    const int*   mask = (const int*)d_in[6];    // [B,LC]
    const int*   qe   = (const int*)d_in[7];    // [B]
    float* out = (float*)d_out;

    float* s_ws = (float*)d_ws;                               // B*LC floats
    float* v_ws = (float*)((char*)d_ws + (1 << 20));          // B*H floats
    float* t_ws = (float*)((char*)d_ws + (1 << 20) + B_ * H_ * 4); // B floats

    k1_proj<<<B_, 256, 0, stream>>>(qr, Wq, bq, Wc, bc, v_ws, t_ws);
    k2_scores<<<dim3(B_, LC_ / 64), 256, 0, stream>>>(ctx, v_ws, t_ws, s_ws);
    k3_project<<<B_, 256, 0, stream>>>(s_ws, mask, qe, out);
}

// Round 2
// 1044.732 us; speedup vs baseline: 1.0468x; 1.0468x over previous
//
#include <hip/hip_runtime.h>

#define B_      64
#define LC_     4096
#define H_      768
#define P_      128
#define MAXLEN_ 4096
#define BUDGET_ 200.0f

// Workspace layout (bytes):
//   s_ws   @ 0                       : B*LC floats  (1 MiB) raw scores (valid rows only)
//   v_ws   @ 1<<20                   : B*H floats   (192 KiB) v[b,h] = q[b,:] . Wc[h,:]
//   t_ws   @ 1<<20 + 196608          : B floats     t[b] = q[b,:] . bc
//   len_ws @ 1<<20 + 196608 + 256    : B ints       len[b] = sum(mask[b,:])

// ---------------- K1: tiny projections -> v, t, len ----------------
__global__ __launch_bounds__(256) void k1_proj(
    const float* __restrict__ qr,   // [B,1,H]
    const float* __restrict__ Wq,   // [H,P]
    const float* __restrict__ bq,   // [P]
    const float* __restrict__ Wc,   // [H,P]
    const float* __restrict__ bc,   // [P]
    const int*   __restrict__ mask, // [B,LC]
    float* __restrict__ v_ws,       // [B,H]
    float* __restrict__ t_ws,       // [B]
    int*   __restrict__ len_ws)     // [B]
{
    const int b    = blockIdx.x;
    const int t    = threadIdx.x;
    const int wid  = t >> 6;
    const int lane = t & 63;

    __shared__ float qr_s[H_];
    __shared__ float part[256];
    __shared__ float q_s[P_];
    __shared__ int   ipart[4];

    for (int h = t; h < H_; h += 256) qr_s[h] = qr[b * H_ + h];
    __syncthreads();

    // q[p] = sum_h qr[h]*Wq[h,p] + bq[p]; h-range split across 2 halves of the block
    const int p    = t & (P_ - 1);
    const int half = t >> 7;
    const int h0   = half * (H_ / 2);
    float acc = 0.f;
    #pragma unroll 8
    for (int h = 0; h < H_ / 2; ++h)
        acc += qr_s[h0 + h] * Wq[(h0 + h) * P_ + p];   // coalesced across p
    part[t] = acc;
    __syncthreads();
    if (t < P_) q_s[t] = part[t] + part[t + P_] + bq[t];
    __syncthreads();

    // v[h] = sum_p q[p] * Wc[h,p]
    const float4* wc4 = reinterpret_cast<const float4*>(Wc);
    for (int h = t; h < H_; h += 256) {
        float a = 0.f;
        #pragma unroll 8
        for (int pp = 0; pp < P_ / 4; ++pp) {
            float4 w = wc4[h * (P_ / 4) + pp];
            a += q_s[pp * 4 + 0] * w.x + q_s[pp * 4 + 1] * w.y
               + q_s[pp * 4 + 2] * w.z + q_s[pp * 4 + 3] * w.w;
        }
        v_ws[b * H_ + h] = a;
    }
    if (t == 0) {
        float tb = 0.f;
        for (int pp = 0; pp < P_; ++pp) tb += q_s[pp] * bc[pp];
        t_ws[b] = tb;
    }

    // len[b] = sum(mask[b,:])
    int lsum = 0;
    for (int i = t; i < LC_; i += 256) lsum += mask[b * LC_ + i];
    #pragma unroll
    for (int off = 32; off; off >>= 1) lsum += __shfl_xor(lsum, off, 64);
    if (lane == 0) ipart[wid] = lsum;
    __syncthreads();
    if (t == 0) len_ws[b] = ipart[0] + ipart[1] + ipart[2] + ipart[3];
}

// ---------------- K2: streaming matvec scores (valid rows only) ----------------
// grid (LC/64, B), block 256 = 4 waves; each wave: 16 rows, one row = 768-dot
__global__ __launch_bounds__(256) void k2_scores(
    const float* __restrict__ ctx,  // [B,LC,H]
    const float* __restrict__ v_ws, // [B,H]
    const float* __restrict__ t_ws, // [B]
    const int*   __restrict__ len_ws, // [B]
    float* __restrict__ s_ws)       // [B,LC]
{
    const int b    = blockIdx.y;
    const int wave = threadIdx.x >> 6;
    const int lane = threadIdx.x & 63;

    const int len = len_ws[b];
    const int j0  = blockIdx.x * 64 + wave * 16;
    if (j0 >= len) return;                       // wave-uniform, no barriers in kernel

    const float4* v4 = reinterpret_cast<const float4*>(v_ws + b * H_);
    const float4 v0 = v4[lane];
    const float4 v1 = v4[64 + lane];
    const float4 v2 = v4[128 + lane];
    const float  tb = t_ws[b];

    const float4* base =
        reinterpret_cast<const float4*>(ctx + ((size_t)b * LC_ + j0) * H_);

    if (j0 + 16 <= len) {
        // full tile fast path
        #pragma unroll 4
        for (int jj = 0; jj < 16; ++jj) {
            const float4* row = base + (size_t)jj * (H_ / 4);
            float4 a = row[lane];
            float4 c = row[64 + lane];
            float4 d = row[128 + lane];
            float acc = a.x * v0.x + a.y * v0.y + a.z * v0.z + a.w * v0.w
                      + c.x * v1.x + c.y * v1.y + c.z * v1.z + c.w * v1.w
                      + d.x * v2.x + d.y * v2.y + d.z * v2.z + d.w * v2.w;
            #pragma unroll
            for (int off = 32; off; off >>= 1) acc += __shfl_xor(acc, off, 64);
            if (lane == 0) s_ws[b * LC_ + j0 + jj] = acc + tb;
        }
    } else {
        const int nrows = len - j0;              // 1..15, wave-uniform
        for (int jj = 0; jj < nrows; ++jj) {
            const float4* row = base + (size_t)jj * (H_ / 4);
            float4 a = row[lane];
            float4 c = row[64 + lane];
            float4 d = row[128 + lane];
            float acc = a.x * v0.x + a.y * v0.y + a.z * v0.z + a.w * v0.w
                      + c.x * v1.x + c.y * v1.y + c.z * v1.z + c.w * v1.w
                      + d.x * v2.x + d.y * v2.y + d.z * v2.z + d.w * v2.w;
            #pragma unroll
            for (int off = 32; off; off >>= 1) acc += __shfl_xor(acc, off, 64);
            if (lane == 0) s_ws[b * LC_ + j0 + jj] = acc + tb;
        }
    }
}

// ---------------- K3: budget projection (bisection) + token scatter ----------------
__global__ __launch_bounds__(256) void k3_project(
    const float* __restrict__ s_ws,   // [B,LC] raw scores (valid rows only)
    const int*   __restrict__ mask,   // [B,LC]
    const int*   __restrict__ qe_arr, // [B]
    float* __restrict__ out)          // [B,MAXLEN]
{
    const int b = blockIdx.x;
    const int t = threadIdx.x;
    const int wid  = t >> 6;
    const int lane = t & 63;

    __shared__ float s_lds[LC_];
    __shared__ float rmin[4], rmax[4], rsum[4];
    __shared__ int   rcnt[4];
    __shared__ float rbuf[2][4];

    float sreg[16];
    float lmin = 1e30f, lmax = -1e30f, lsum = 0.f;
    int   lcnt = 0;

    #pragma unroll
    for (int k = 0; k < 16; ++k) {
        const int i = t + k * 256;
        const int m = mask[b * LC_ + i];
        const float sv = s_ws[b * LC_ + i];
        const float val = m ? sv : -100000.0f;   // exact -1e5 sentinel at pads (TEMP=1)
        sreg[k] = val;
        s_lds[i] = val;
        lmin = fminf(lmin, val);
        lmax = fmaxf(lmax, val);
        lsum += fminf(fmaxf(val, 0.f), 1.f);
        lcnt += m;
    }

    // block reduce min/max/feasible-sum/mask-count
    #pragma unroll
    for (int off = 32; off; off >>= 1) {
        lmin = fminf(lmin, __shfl_xor(lmin, off, 64));
        lmax = fmaxf(lmax, __shfl_xor(lmax, off, 64));
        lsum += __shfl_xor(lsum, off, 64);
        lcnt += __shfl_xor(lcnt, off, 64);
    }
    if (lane == 0) { rmin[wid] = lmin; rmax[wid] = lmax; rsum[wid] = lsum; rcnt[wid] = lcnt; }
    __syncthreads();
    const float gmin = fminf(fminf(rmin[0], rmin[1]), fminf(rmin[2], rmin[3]));
    const float gmax = fmaxf(fmaxf(rmax[0], rmax[1]), fmaxf(rmax[2], rmax[3]));
    const float gsum = rsum[0] + rsum[1] + rsum[2] + rsum[3];
    const int   gcnt = rcnt[0] + rcnt[1] + rcnt[2] + rcnt[3];

    const bool feasible = (gsum <= BUDGET_);
    float lo = gmin - 1.f;
    float hi = gmax;

    // 100 bisection iterations, one barrier each (double-buffered partials)
    for (int it = 0; it < 100; ++it) {
        const float mid = 0.5f * (lo + hi);
        float ps = 0.f;
        #pragma unroll
        for (int k = 0; k < 16; ++k)
            ps += fminf(fmaxf(sreg[k] - mid, 0.f), 1.f);
        #pragma unroll
        for (int off = 32; off; off >>= 1) ps += __shfl_xor(ps, off, 64);
        if (lane == 0) rbuf[it & 1][wid] = ps;
        __syncthreads();
        const float total = rbuf[it & 1][0] + rbuf[it & 1][1]
                          + rbuf[it & 1][2] + rbuf[it & 1][3];
        if (total > BUDGET_) lo = mid; else hi = mid;
    }

    const float tau  = feasible ? 0.f : 0.5f * (lo + hi);
    const int   qe   = qe_arr[b];
    const int   clen = gcnt - 1;   // context_length

    #pragma unroll
    for (int k = 0; k < 16; ++k) {
        const int pos = t + k * 256;
        const int idx = pos - qe + 1;
        float o;
        if (pos < qe)                        o = 1.f;
        else if (idx >= 1 && idx <= clen)    o = fminf(fmaxf(s_lds[idx] - tau, 0.f), 1.f);
        else                                 o = 0.f;
        out[b * MAXLEN_ + pos] = o;
    }
}

extern "C" void kernel_launch(void* const* d_in, const int* in_sizes, int n_in,
                              void* d_out, int out_size, void* d_ws, size_t ws_size,
                              hipStream_t stream) {
    const float* qr   = (const float*)d_in[0];  // question_reps [B,1,H]
    const float* ctx  = (const float*)d_in[1];  // context_reps  [B,LC,H]
    const float* Wq   = (const float*)d_in[2];  // [H,P]
    const float* bq   = (const float*)d_in[3];  // [P]
    const float* Wc   = (const float*)d_in[4];  // [H,P]
    const float* bc   = (const float*)d_in[5];  // [P]
    const int*   mask = (const int*)d_in[6];    // [B,LC]
    const int*   qe   = (const int*)d_in[7];    // [B]
    float* out = (float*)d_out;

    float* s_ws   = (float*)d_ws;                                    // B*LC floats
    float* v_ws   = (float*)((char*)d_ws + (1 << 20));               // B*H floats
    float* t_ws   = (float*)((char*)d_ws + (1 << 20) + B_ * H_ * 4); // B floats
    int*   len_ws = (int*)  ((char*)d_ws + (1 << 20) + B_ * H_ * 4 + 256); // B ints

    k1_proj<<<B_, 256, 0, stream>>>(qr, Wq, bq, Wc, bc, mask, v_ws, t_ws, len_ws);
    k2_scores<<<dim3(LC_ / 64, B_), 256, 0, stream>>>(ctx, v_ws, t_ws, len_ws, s_ws);
    k3_project<<<B_, 256, 0, stream>>>(s_ws, mask, qe, out);
}